// Round 1
// baseline (8097.974 us; speedup 1.0000x reference)
//
#include <hip/hip_runtime.h>
#include <hip/hip_bf16.h>

#define DI __device__ __forceinline__

typedef short bf16x8 __attribute__((ext_vector_type(8)));
typedef float f32x4 __attribute__((ext_vector_type(4)));

constexpr int B_ = 2048, T_ = 120, V_ = 64, E_ = 128, H_ = 512, LAT_ = 256;
constexpr int H3 = 1536;  // 3*H

DI short f2b(float f) {
  union { __hip_bfloat16 h; short s; } u;
  u.h = __float2bfloat16(f);
  return u.s;
}
DI float sigm(float x) { return 1.f / (1.f + __expf(-x)); }
DI float tanh_f(float x) {
  x = fminf(15.f, fmaxf(-15.f, x));
  float e = __expf(2.f * x);
  return (e - 1.f) / (e + 1.f);
}
DI float gru_one(float xr, float xz, float xn, float hr, float hz, float hn, float hp) {
  float r = sigm(xr + hr);
  float u = sigm(xz + hz);
  float nn = tanh_f(xn + r * hn);
  return (1.f - u) * nn + u * hp;
}
DI float4 add4(float4 a, const float4& b) {
  a.x += b.x; a.y += b.y; a.z += b.z; a.w += b.w; return a;
}
DI float4 gru4(const float4& xr, const float4& xz, const float4& xn,
               const float4& hr, const float4& hz, const float4& hn, const float4& hp) {
  float4 o;
  o.x = gru_one(xr.x, xz.x, xn.x, hr.x, hz.x, hn.x, hp.x);
  o.y = gru_one(xr.y, xz.y, xn.y, hr.y, hz.y, hn.y, hp.y);
  o.z = gru_one(xr.z, xz.z, xn.z, hr.z, hz.z, hn.z, hp.z);
  o.w = gru_one(xr.w, xz.w, xn.w, hr.w, hz.w, hn.w, hp.w);
  return o;
}
DI void pack4(short* dst, const float4& v) {
  unsigned int lo = (unsigned int)(unsigned short)f2b(v.x) |
                    ((unsigned int)(unsigned short)f2b(v.y) << 16);
  unsigned int hi = (unsigned int)(unsigned short)f2b(v.z) |
                    ((unsigned int)(unsigned short)f2b(v.w) << 16);
  *(uint2*)dst = make_uint2(lo, hi);
}

// ---- 128x128 MFMA tile: C[128x128] += A[128xK] * W[128xK]^T (both row-major, K-contig)
// Block = 256 threads = 4 waves (2x2 of 64x64). Fragments loaded directly from global.
// Layouts (guide §3, m89-verified): A/B: lane l holds row/col (l&15), k=(l>>4)*8+e.
// D: col = lane&15, row = (lane>>4)*4 + reg.
DI void gemm_acc_128(const short* __restrict__ A, const short* __restrict__ W,
                     int K, int mbase, int nbase, f32x4 acc[4][4]) {
  const int tid = threadIdx.x;
  const int lane = tid & 63, wid = tid >> 6;
  const int wm = wid >> 1, wn = wid & 1;
  const int r = lane & 15, ko = (lane >> 4) * 8;
  const short* Ap = A + (size_t)(mbase + wm * 64 + r) * K + ko;
  const short* Wp = W + (size_t)(nbase + wn * 64 + r) * K + ko;
  for (int kk = 0; kk < K; kk += 32) {
    bf16x8 a[4], b[4];
#pragma unroll
    for (int i = 0; i < 4; ++i) a[i] = *(const bf16x8*)(Ap + (size_t)i * 16 * K + kk);
#pragma unroll
    for (int j = 0; j < 4; ++j) b[j] = *(const bf16x8*)(Wp + (size_t)j * 16 * K + kk);
#pragma unroll
    for (int i = 0; i < 4; ++i)
#pragma unroll
      for (int j = 0; j < 4; ++j)
        acc[i][j] = __builtin_amdgcn_mfma_f32_16x16x32_bf16(a[i], b[j], acc[i][j], 0, 0, 0);
  }
}

DI void epi_bias_store(float* __restrict__ C, const float* __restrict__ bias,
                       int N, int mbase, int nbase, f32x4 acc[4][4]) {
  const int tid = threadIdx.x, lane = tid & 63, wid = tid >> 6;
  const int wm = wid >> 1, wn = wid & 1;
  const int r0 = (lane >> 4) * 4, c0 = lane & 15;
#pragma unroll
  for (int i = 0; i < 4; ++i)
#pragma unroll
    for (int j = 0; j < 4; ++j) {
      int col = nbase + wn * 64 + j * 16 + c0;
      float bv = bias[col];
      int rowb = mbase + wm * 64 + i * 16 + r0;
#pragma unroll
      for (int rr = 0; rr < 4; ++rr)
        C[(size_t)(rowb + rr) * N + col] = acc[i][j][rr] + bv;
    }
}

// ---- prep0: bf16 conversions of all weight matrices + z
__global__ __launch_bounds__(256) void k_prep0(
    const float* __restrict__ W_hh0, const float* __restrict__ W_ih1,
    const float* __restrict__ W_hh1, const float* __restrict__ fc_out_w,
    const float* __restrict__ W_ih0, const float* __restrict__ fc_hidden_w,
    const float* __restrict__ z,
    short* Wb_hh0, short* Wb_ih1, short* Wb_hh1, short* Wb_out,
    short* Wb_ih0z, short* Wb_fch, short* z_b) {
  const int n1 = H3 * H_;          // 786432
  const int n2 = V_ * H_;          // 32768
  const int n3 = H3 * LAT_;        // 393216
  const int n4 = (2 * H_) * LAT_;  // 262144
  const int n5 = B_ * LAT_;        // 524288
  const int total = n1 * 3 + n2 + n3 + n4 + n5;
  for (int i = blockIdx.x * blockDim.x + threadIdx.x; i < total;
       i += gridDim.x * blockDim.x) {
    int idx = i;
    if (idx < n1) { Wb_hh0[idx] = f2b(W_hh0[idx]); continue; }
    idx -= n1;
    if (idx < n1) { Wb_ih1[idx] = f2b(W_ih1[idx]); continue; }
    idx -= n1;
    if (idx < n1) { Wb_hh1[idx] = f2b(W_hh1[idx]); continue; }
    idx -= n1;
    if (idx < n2) { Wb_out[idx] = f2b(fc_out_w[idx]); continue; }
    idx -= n2;
    if (idx < n3) {
      int n = idx >> 8, k = idx & 255;
      Wb_ih0z[idx] = f2b(W_ih0[(size_t)n * (E_ + LAT_) + E_ + k]);
      continue;
    }
    idx -= n3;
    if (idx < n4) { Wb_fch[idx] = f2b(fc_hidden_w[idx]); continue; }
    idx -= n4;
    z_b[idx] = f2b(z[idx]);
  }
}

// ---- emb_gx[v][n] = sum_e embed[v][e] * W_ih0[n][e]   (fp32, tiny)
__global__ __launch_bounds__(256) void k_prep_emb(const float* __restrict__ embed,
                                                  const float* __restrict__ W_ih0,
                                                  float* __restrict__ egx) {
  __shared__ float er[E_];
  int v = blockIdx.x;
  for (int e = threadIdx.x; e < E_; e += blockDim.x) er[e] = embed[(size_t)v * E_ + e];
  __syncthreads();
  for (int n = threadIdx.x; n < H3; n += blockDim.x) {
    const float* w = W_ih0 + (size_t)n * (E_ + LAT_);
    float acc = 0.f;
#pragma unroll 8
    for (int e = 0; e < E_; ++e) acc += er[e] * w[e];
    egx[(size_t)v * H3 + n] = acc;
  }
}

// ---- prep1: z_gx = z@W_ih0[:,E:]^T + b_ih0 ; hid = z@fc_hidden_w^T + fc_hidden_b -> h0,h1
__global__ __launch_bounds__(256) void k_prep1(
    const short* __restrict__ z_b, const short* __restrict__ Wb_ih0z,
    const short* __restrict__ Wb_fch, const float* __restrict__ b_ih0,
    const float* __restrict__ fc_hidden_b,
    float* zgx, float* h0f, float* h1f, short* h0b, short* h1b) {
  int bid = blockIdx.x;
  int mtile = bid / 20, ntile = bid % 20;
  int mbase = mtile * 128;
  f32x4 acc[4][4] = {};
  if (ntile < 12) {
    int nbase = ntile * 128;
    gemm_acc_128(z_b, Wb_ih0z, LAT_, mbase, nbase, acc);
    epi_bias_store(zgx, b_ih0, H3, mbase, nbase, acc);
  } else {
    int nbase = (ntile - 12) * 128;  // within [0,1024)
    gemm_acc_128(z_b, Wb_fch + (size_t)nbase * LAT_, LAT_, mbase, 0, acc);
    const int tid = threadIdx.x, lane = tid & 63, wid = tid >> 6;
    const int wm = wid >> 1, wn = wid & 1;
    const int r0 = (lane >> 4) * 4, c0 = lane & 15;
#pragma unroll
    for (int i = 0; i < 4; ++i)
#pragma unroll
      for (int j = 0; j < 4; ++j) {
        int col = nbase + wn * 64 + j * 16 + c0;
        float bv = fc_hidden_b[col];
        int rowb = mbase + wm * 64 + i * 16 + r0;
#pragma unroll
        for (int rr = 0; rr < 4; ++rr) {
          int row = rowb + rr;
          float v = acc[i][j][rr] + bv;
          if (col < H_) {
            h0f[(size_t)row * H_ + col] = v;
            h0b[(size_t)row * H_ + col] = f2b(v);
          } else {
            h1f[(size_t)row * H_ + (col - H_)] = v;
            h1b[(size_t)row * H_ + (col - H_)] = f2b(v);
          }
        }
      }
  }
}

// ---- phase X: gh0(t) GEMM  ||  pw1(t-1) + logits(t-1)
__global__ __launch_bounds__(256) void k_phaseX(
    const short* __restrict__ h0b, const short* __restrict__ Wb_hh0,
    const float* __restrict__ b_hh0, float* __restrict__ gh0,
    int gemm_blocks, int t,
    const float* __restrict__ gx1, const float* __restrict__ gh1,
    float* __restrict__ h1f, short* __restrict__ h1b,
    const short* __restrict__ Wb_out, const float* __restrict__ fc_out_b,
    float* __restrict__ out) {
  int bid = blockIdx.x;
  if (bid < gemm_blocks) {
    f32x4 acc[4][4] = {};
    int mtile = bid / 12, ntile = bid % 12;
    gemm_acc_128(h0b, Wb_hh0, H_, mtile * 128, ntile * 128, acc);
    epi_bias_store(gh0, b_hh0, H3, mtile * 128, ntile * 128, acc);
    return;
  }
  // pw1 + logits for step (t-1); 16 rows per block, 128 blocks
  __shared__ short sh[16 * 520];  // padded stride to spread LDS banks
  const int pwblk = bid - gemm_blocks;
  const int row0 = pwblk * 16;
  const int tid = threadIdx.x;
  const int tlog = t - 1;
#pragma unroll 1
  for (int c = 0; c < 8; ++c) {
    int f = c * 1024 + tid * 4;
    int rl = f >> 9, j = f & 511;
    int row = row0 + rl;
    size_t b3 = (size_t)row * H3 + j;
    size_t bh = (size_t)row * H_ + j;
    float4 xr = *(const float4*)(gx1 + b3);
    float4 xz = *(const float4*)(gx1 + b3 + H_);
    float4 xn = *(const float4*)(gx1 + b3 + 2 * H_);
    float4 hr = *(const float4*)(gh1 + b3);
    float4 hz = *(const float4*)(gh1 + b3 + H_);
    float4 hn = *(const float4*)(gh1 + b3 + 2 * H_);
    float4 hp = *(const float4*)(h1f + bh);
    float4 hv = gru4(xr, xz, xn, hr, hz, hn, hp);
    *(float4*)(h1f + bh) = hv;
    pack4(h1b + bh, hv);
    pack4(&sh[rl * 520 + j], hv);
  }
  __syncthreads();
  // logits: 16 rows x 64 cols, K=512. wave w -> col frag w.
  const int lane = tid & 63, w = tid >> 6;
  const int c0 = lane & 15, ko = (lane >> 4) * 8;
  f32x4 acc = {};
  const short* wb = Wb_out + (size_t)(w * 16 + c0) * H_ + ko;
  const short* ap = &sh[c0 * 520 + ko];
#pragma unroll
  for (int m = 0; m < 16; ++m) {
    bf16x8 a = *(const bf16x8*)(ap + m * 32);
    bf16x8 bw = *(const bf16x8*)(wb + m * 32);
    acc = __builtin_amdgcn_mfma_f32_16x16x32_bf16(a, bw, acc, 0, 0, 0);
  }
  const int r0 = (lane >> 4) * 4;
  const int col = w * 16 + c0;
  const float bv = fc_out_b[col];
#pragma unroll
  for (int rr = 0; rr < 4; ++rr) {
    int brow = row0 + r0 + rr;
    out[((size_t)brow * T_ + tlog) * V_ + col] = acc[rr] + bv;
  }
}

// ---- phase Y: gh1(t) GEMM  ||  pw0(t)
__global__ __launch_bounds__(256) void k_phaseY(
    const short* __restrict__ h1b, const short* __restrict__ Wb_hh1,
    const float* __restrict__ b_hh1, float* __restrict__ gh1,
    int t, const float* __restrict__ gh0, const float* __restrict__ zgx,
    const float* __restrict__ egx, const int* __restrict__ target,
    float* __restrict__ h0f, short* __restrict__ h0b) {
  int bid = blockIdx.x;
  if (bid < 192) {
    f32x4 acc[4][4] = {};
    int mtile = bid / 12, ntile = bid % 12;
    gemm_acc_128(h1b, Wb_hh1, H_, mtile * 128, ntile * 128, acc);
    epi_bias_store(gh1, b_hh1, H3, mtile * 128, ntile * 128, acc);
    return;
  }
  // pw0: 32 rows per block, 64 blocks
  const int pwblk = bid - 192;
  const int row0 = pwblk * 32;
  const int tid = threadIdx.x;
#pragma unroll 1
  for (int c = 0; c < 16; ++c) {
    int f = c * 1024 + tid * 4;
    int rl = f >> 9, j = f & 511;
    int row = row0 + rl;
    int tok = (t == 0) ? 1 : target[(size_t)row * T_ + (t - 1)];
    size_t b3 = (size_t)row * H3 + j;
    size_t e3 = (size_t)tok * H3 + j;
    size_t bh = (size_t)row * H_ + j;
    float4 xr = *(const float4*)(zgx + b3);
    float4 xz = *(const float4*)(zgx + b3 + H_);
    float4 xn = *(const float4*)(zgx + b3 + 2 * H_);
    float4 er = *(const float4*)(egx + e3);
    float4 ez = *(const float4*)(egx + e3 + H_);
    float4 en = *(const float4*)(egx + e3 + 2 * H_);
    float4 hr = *(const float4*)(gh0 + b3);
    float4 hz = *(const float4*)(gh0 + b3 + H_);
    float4 hn = *(const float4*)(gh0 + b3 + 2 * H_);
    float4 hp = *(const float4*)(h0f + bh);
    float4 hv = gru4(add4(xr, er), add4(xz, ez), add4(xn, en), hr, hz, hn, hp);
    *(float4*)(h0f + bh) = hv;
    pack4(h0b + bh, hv);
  }
}

// ---- phase Z: gx1(t) = h0n @ W_ih1^T + b_ih1
__global__ __launch_bounds__(256) void k_phaseZ(
    const short* __restrict__ h0b, const short* __restrict__ Wb_ih1,
    const float* __restrict__ b_ih1, float* __restrict__ gx1) {
  f32x4 acc[4][4] = {};
  int mtile = blockIdx.x / 12, ntile = blockIdx.x % 12;
  gemm_acc_128(h0b, Wb_ih1, H_, mtile * 128, ntile * 128, acc);
  epi_bias_store(gx1, b_ih1, H3, mtile * 128, ntile * 128, acc);
}

extern "C" void kernel_launch(void* const* d_in, const int* in_sizes, int n_in,
                              void* d_out, int out_size, void* d_ws, size_t ws_size,
                              hipStream_t stream) {
  const float* z           = (const float*)d_in[0];
  const int*   target      = (const int*)d_in[1];
  const float* embed       = (const float*)d_in[2];
  const float* fc_hidden_w = (const float*)d_in[3];
  const float* fc_hidden_b = (const float*)d_in[4];
  const float* W_ih0       = (const float*)d_in[5];
  const float* W_hh0       = (const float*)d_in[6];
  const float* b_ih0       = (const float*)d_in[7];
  const float* b_hh0       = (const float*)d_in[8];
  const float* W_ih1       = (const float*)d_in[9];
  const float* W_hh1       = (const float*)d_in[10];
  const float* b_ih1       = (const float*)d_in[11];
  const float* b_hh1       = (const float*)d_in[12];
  const float* fc_out_w    = (const float*)d_in[13];
  const float* fc_out_b    = (const float*)d_in[14];
  float* out = (float*)d_out;

  char* ws = (char*)d_ws;
  size_t off = 0;
  auto alloc = [&](size_t bytes) -> void* {
    off = (off + 255) & ~(size_t)255;
    void* p = ws + off;
    off += bytes;
    return p;
  };
  float* h0f    = (float*)alloc((size_t)B_ * H_ * 4);
  float* h1f    = (float*)alloc((size_t)B_ * H_ * 4);
  short* h0b    = (short*)alloc((size_t)B_ * H_ * 2);
  short* h1b    = (short*)alloc((size_t)B_ * H_ * 2);
  float* gh0    = (float*)alloc((size_t)B_ * H3 * 4);
  float* gh1    = (float*)alloc((size_t)B_ * H3 * 4);
  float* gx1    = (float*)alloc((size_t)B_ * H3 * 4);
  float* zgx    = (float*)alloc((size_t)B_ * H3 * 4);
  float* egx    = (float*)alloc((size_t)V_ * H3 * 4);
  short* Wb_hh0 = (short*)alloc((size_t)H3 * H_ * 2);
  short* Wb_ih1 = (short*)alloc((size_t)H3 * H_ * 2);
  short* Wb_hh1 = (short*)alloc((size_t)H3 * H_ * 2);
  short* Wb_out = (short*)alloc((size_t)V_ * H_ * 2);
  short* Wb_ih0z= (short*)alloc((size_t)H3 * LAT_ * 2);
  short* Wb_fch = (short*)alloc((size_t)2 * H_ * LAT_ * 2);
  short* z_b    = (short*)alloc((size_t)B_ * LAT_ * 2);
  if (off > ws_size) return;  // workspace too small -> fail visibly (poisoned out)

  k_prep0<<<2048, 256, 0, stream>>>(W_hh0, W_ih1, W_hh1, fc_out_w, W_ih0, fc_hidden_w,
                                    z, Wb_hh0, Wb_ih1, Wb_hh1, Wb_out, Wb_ih0z, Wb_fch, z_b);
  k_prep_emb<<<64, 256, 0, stream>>>(embed, W_ih0, egx);
  k_prep1<<<320, 256, 0, stream>>>(z_b, Wb_ih0z, Wb_fch, b_ih0, fc_hidden_b,
                                   zgx, h0f, h1f, h0b, h1b);

  for (int t = 0; t < T_; ++t) {
    int gridX = (t == 0) ? 192 : 320;
    k_phaseX<<<gridX, 256, 0, stream>>>(h0b, Wb_hh0, b_hh0, gh0, 192, t,
                                        gx1, gh1, h1f, h1b, Wb_out, fc_out_b, out);
    k_phaseY<<<256, 256, 0, stream>>>(h1b, Wb_hh1, b_hh1, gh1, t, gh0, zgx, egx,
                                      target, h0f, h0b);
    k_phaseZ<<<192, 256, 0, stream>>>(h0b, Wb_ih1, b_ih1, gx1);
  }
  // final pw1 + logits for t = T-1
  k_phaseX<<<128, 256, 0, stream>>>(h0b, Wb_hh0, b_hh0, gh0, 0, T_,
                                    gx1, gh1, h1f, h1b, Wb_out, fc_out_b, out);
}

// Round 2
// 7655.865 us; speedup vs baseline: 1.0577x; 1.0577x over previous
//
#include <hip/hip_runtime.h>
#include <hip/hip_bf16.h>

#define DI __device__ __forceinline__

typedef short bf16x8 __attribute__((ext_vector_type(8)));
typedef float f32x4 __attribute__((ext_vector_type(4)));

constexpr int B_ = 2048, T_ = 120, V_ = 64, E_ = 128, H_ = 512, LAT_ = 256;
constexpr int H3 = 1536;  // 3*H

DI short f2b(float f) {
  union { __hip_bfloat16 h; short s; } u;
  u.h = __float2bfloat16(f);
  return u.s;
}
DI float b2f(short s) {
  union { unsigned u; float f; } x;
  x.u = (unsigned)(unsigned short)s << 16;
  return x.f;
}
DI float sigm(float x) { return 1.f / (1.f + __expf(-x)); }
DI float tanh_f(float x) {
  x = fminf(15.f, fmaxf(-15.f, x));
  float e = __expf(2.f * x);
  return (e - 1.f) / (e + 1.f);
}
DI float gru_one(float xr, float xz, float xn, float hr, float hz, float hn, float hp) {
  float r = sigm(xr + hr);
  float u = sigm(xz + hz);
  float nn = tanh_f(xn + r * hn);
  return (1.f - u) * nn + u * hp;
}

// ================= wave-level MFMA primitives =================
// A/B frag (16x16x32 bf16): lane l holds row/col (l&15), k = (l>>4)*8 + e.
// C/D: col = lane&15, row = (lane>>4)*4 + reg.
template <int MI, int NJ>
DI void gemm_wave_global(const short* __restrict__ A, const short* __restrict__ B,
                         const int K, const int arow, const int bcol,
                         f32x4 (&acc)[MI][NJ]) {
  const int lane = threadIdx.x & 63;
  const int r = lane & 15, ko = (lane >> 4) * 8;
  const short* Ap = A + (size_t)(arow + r) * K + ko;
  const short* Bp = B + (size_t)(bcol + r) * K + ko;
  for (int kk = 0; kk < K; kk += 32) {
    bf16x8 a[MI], b[NJ];
#pragma unroll
    for (int i = 0; i < MI; ++i) a[i] = *(const bf16x8*)(Ap + (size_t)i * 16 * K + kk);
#pragma unroll
    for (int j = 0; j < NJ; ++j) b[j] = *(const bf16x8*)(Bp + (size_t)j * 16 * K + kk);
#pragma unroll
    for (int i = 0; i < MI; ++i)
#pragma unroll
      for (int j = 0; j < NJ; ++j)
        acc[i][j] = __builtin_amdgcn_mfma_f32_16x16x32_bf16(a[i], b[j], acc[i][j], 0, 0, 0);
  }
}

// A staged in LDS as [rows][512] bf16 with XOR swizzle: byte = (row<<10) + ((k*2) ^ ((row&7)<<4))
template <int MI, int NJ>
DI void gemm_wave_ldsA(const char* __restrict__ lds, const short* __restrict__ B,
                       const int arowl, const int bcol, f32x4 (&acc)[MI][NJ]) {
  const int lane = threadIdx.x & 63;
  const int r = lane & 15, ko = (lane >> 4) * 8;
  const short* Bp = B + (size_t)(bcol + r) * H_ + ko;
  int abase[MI], aswz[MI];
#pragma unroll
  for (int i = 0; i < MI; ++i) {
    int rowl = arowl + i * 16 + r;
    abase[i] = rowl << 10;
    aswz[i] = (rowl & 7) << 4;
  }
  for (int kk = 0; kk < H_; kk += 32) {
    bf16x8 a[MI], b[NJ];
#pragma unroll
    for (int i = 0; i < MI; ++i)
      a[i] = *(const bf16x8*)(lds + abase[i] + ((((kk + ko) << 1)) ^ aswz[i]));
#pragma unroll
    for (int j = 0; j < NJ; ++j) b[j] = *(const bf16x8*)(Bp + (size_t)j * 16 * H_ + kk);
#pragma unroll
    for (int i = 0; i < MI; ++i)
#pragma unroll
      for (int j = 0; j < NJ; ++j)
        acc[i][j] = __builtin_amdgcn_mfma_f32_16x16x32_bf16(a[i], b[j], acc[i][j], 0, 0, 0);
  }
}

template <int MI, int NJ>
DI void epi_store_bf16(short* __restrict__ C, const float* __restrict__ bias,
                       const int N, const int arow, const int bcol, f32x4 (&acc)[MI][NJ]) {
  const int lane = threadIdx.x & 63;
  const int r0 = (lane >> 4) * 4, c0 = lane & 15;
#pragma unroll
  for (int i = 0; i < MI; ++i)
#pragma unroll
    for (int j = 0; j < NJ; ++j) {
      int col = bcol + j * 16 + c0;
      float bv = bias[col];
#pragma unroll
      for (int rr = 0; rr < 4; ++rr)
        C[(size_t)(arow + i * 16 + r0 + rr) * N + col] = f2b(acc[i][j][rr] + bv);
    }
}

// ================= prep kernels =================
__global__ __launch_bounds__(256) void k_prep0(
    const float* __restrict__ W_hh0, const float* __restrict__ W_ih1,
    const float* __restrict__ W_hh1, const float* __restrict__ fc_out_w,
    const float* __restrict__ W_ih0, const float* __restrict__ fc_hidden_w,
    const float* __restrict__ z,
    short* Wb_hh0, short* Wb_ih1, short* Wb_hh1, short* Wb_out,
    short* Wb_ih0z, short* Wb_fch, short* z_b) {
  const int n1 = H3 * H_;
  const int n2 = V_ * H_;
  const int n3 = H3 * LAT_;
  const int n4 = (2 * H_) * LAT_;
  const int n5 = B_ * LAT_;
  const int total = n1 * 3 + n2 + n3 + n4 + n5;
  for (int i = blockIdx.x * blockDim.x + threadIdx.x; i < total;
       i += gridDim.x * blockDim.x) {
    int idx = i;
    if (idx < n1) { Wb_hh0[idx] = f2b(W_hh0[idx]); continue; }
    idx -= n1;
    if (idx < n1) { Wb_ih1[idx] = f2b(W_ih1[idx]); continue; }
    idx -= n1;
    if (idx < n1) { Wb_hh1[idx] = f2b(W_hh1[idx]); continue; }
    idx -= n1;
    if (idx < n2) { Wb_out[idx] = f2b(fc_out_w[idx]); continue; }
    idx -= n2;
    if (idx < n3) {
      int n = idx >> 8, k = idx & 255;
      Wb_ih0z[idx] = f2b(W_ih0[(size_t)n * (E_ + LAT_) + E_ + k]);
      continue;
    }
    idx -= n3;
    if (idx < n4) { Wb_fch[idx] = f2b(fc_hidden_w[idx]); continue; }
    idx -= n4;
    z_b[idx] = f2b(z[idx]);
  }
}

__global__ __launch_bounds__(256) void k_prep_emb(const float* __restrict__ embed,
                                                  const float* __restrict__ W_ih0,
                                                  short* __restrict__ egx) {
  __shared__ float er[E_];
  int v = blockIdx.x;
  for (int e = threadIdx.x; e < E_; e += blockDim.x) er[e] = embed[(size_t)v * E_ + e];
  __syncthreads();
  for (int n = threadIdx.x; n < H3; n += blockDim.x) {
    const float* w = W_ih0 + (size_t)n * (E_ + LAT_);
    float acc = 0.f;
#pragma unroll 8
    for (int e = 0; e < E_; ++e) acc += er[e] * w[e];
    egx[(size_t)v * H3 + n] = f2b(acc);
  }
}

// prep1: zgx = z@W_ih0[:,E:]^T + b_ih0 (bf16); hid = z@fc_hidden_w^T + b -> h0,h1 init (buf0)
__global__ __launch_bounds__(256) void k_prep1(
    const short* __restrict__ z_b, const short* __restrict__ Wb_ih0z,
    const short* __restrict__ Wb_fch, const float* __restrict__ b_ih0,
    const float* __restrict__ fc_hidden_b,
    short* zgx, float* h0f, float* h1f, short* h0b, short* h1b) {
  const int bid = blockIdx.x;
  const int mtile = bid / 20, ntile = bid % 20;
  const int tid = threadIdx.x, lane = tid & 63, wid = tid >> 6;
  const int wm = wid >> 1, wn = wid & 1;
  const int arow = mtile * 128 + wm * 64;
  f32x4 acc[4][4] = {};
  if (ntile < 12) {
    int bcol = ntile * 128 + wn * 64;
    gemm_wave_global<4, 4>(z_b, Wb_ih0z, LAT_, arow, bcol, acc);
    epi_store_bf16<4, 4>(zgx, b_ih0, H3, arow, bcol, acc);
  } else {
    int bcol = (ntile - 12) * 128 + wn * 64;  // within [0,1024)
    gemm_wave_global<4, 4>(z_b, Wb_fch, LAT_, arow, bcol, acc);
    const int r0 = (lane >> 4) * 4, c0 = lane & 15;
#pragma unroll
    for (int i = 0; i < 4; ++i)
#pragma unroll
      for (int j = 0; j < 4; ++j) {
        int col = bcol + j * 16 + c0;
        float bv = fc_hidden_b[col];
#pragma unroll
        for (int rr = 0; rr < 4; ++rr) {
          int row = arow + i * 16 + r0 + rr;
          float v = acc[i][j][rr] + bv;
          if (col < H_) {
            h0f[(size_t)row * H_ + col] = v;
            h0b[(size_t)row * H_ + col] = f2b(v);
          } else {
            h1f[(size_t)row * H_ + (col - H_)] = v;
            h1b[(size_t)row * H_ + (col - H_)] = f2b(v);
          }
        }
      }
  }
}

// ================= D1: gh0(t) GEMM || pw1(t-1)+logits(t-1) =================
__global__ __launch_bounds__(256) void k_D1(
    const short* __restrict__ h0b_cur, const short* __restrict__ Wb_hh0,
    const float* __restrict__ b_hh0, short* __restrict__ gh0,
    const int gblocks, const int t,
    const short* __restrict__ gx1, const short* __restrict__ gh1,
    float* __restrict__ h1f, short* __restrict__ h1b,
    const short* __restrict__ Wb_out, const float* __restrict__ fc_out_b,
    float* __restrict__ out) {
  const int bid = blockIdx.x;
  const int tid = threadIdx.x;
  if (bid < gblocks) {
    const int lane = tid & 63, wid = tid >> 6;
    const int wm = wid >> 1, wn = wid & 1;
    const int mt = bid / 12, nt = bid % 12;
    const int arow = mt * 64 + wm * 32;
    const int bcol = nt * 128 + wn * 64;
    f32x4 acc[2][4] = {};
    gemm_wave_global<2, 4>(h0b_cur, Wb_hh0, H_, arow, bcol, acc);
    epi_store_bf16<2, 4>(gh0, b_hh0, H3, arow, bcol, acc);
    return;
  }
  // pw1 + logits for step t-1; 16 rows per block
  __shared__ __align__(16) short sh[16 * 520];
  const int pwblk = bid - gblocks;
  const int row0 = pwblk * 16;
  const int tlog = t - 1;
#pragma unroll 1
  for (int c = 0; c < 4; ++c) {
    int f = c * 2048 + tid * 8;
    int rl = f >> 9, j = f & 511;
    int row = row0 + rl;
    const short* gx = gx1 + (size_t)row * H3 + j;
    const short* gh = gh1 + (size_t)row * H3 + j;
    float* hf = h1f + (size_t)row * H_ + j;
    bf16x8 xr = *(const bf16x8*)(gx);
    bf16x8 xz = *(const bf16x8*)(gx + H_);
    bf16x8 xn = *(const bf16x8*)(gx + 2 * H_);
    bf16x8 hr = *(const bf16x8*)(gh);
    bf16x8 hz = *(const bf16x8*)(gh + H_);
    bf16x8 hn = *(const bf16x8*)(gh + 2 * H_);
    float4 hp0 = *(const float4*)(hf);
    float4 hp1 = *(const float4*)(hf + 4);
    float hp[8] = {hp0.x, hp0.y, hp0.z, hp0.w, hp1.x, hp1.y, hp1.z, hp1.w};
    float hv[8];
    bf16x8 ov;
#pragma unroll
    for (int e = 0; e < 8; ++e) {
      hv[e] = gru_one(b2f(xr[e]), b2f(xz[e]), b2f(xn[e]),
                      b2f(hr[e]), b2f(hz[e]), b2f(hn[e]), hp[e]);
      ov[e] = f2b(hv[e]);
    }
    *(float4*)(hf) = make_float4(hv[0], hv[1], hv[2], hv[3]);
    *(float4*)(hf + 4) = make_float4(hv[4], hv[5], hv[6], hv[7]);
    *(bf16x8*)(h1b + (size_t)row * H_ + j) = ov;
    *(bf16x8*)(&sh[rl * 520 + j]) = ov;
  }
  __syncthreads();
  // logits: 16 rows x 64 cols, K=512; wave w handles cols w*16..w*16+15
  const int lane = tid & 63, w = tid >> 6;
  const int c0 = lane & 15, ko = (lane >> 4) * 8;
  f32x4 acc = {};
  const short* wb = Wb_out + (size_t)(w * 16 + c0) * H_ + ko;
  const short* ap = &sh[c0 * 520 + ko];
#pragma unroll
  for (int m = 0; m < 16; ++m) {
    bf16x8 a = *(const bf16x8*)(ap + m * 32);
    bf16x8 bw = *(const bf16x8*)(wb + m * 32);
    acc = __builtin_amdgcn_mfma_f32_16x16x32_bf16(a, bw, acc, 0, 0, 0);
  }
  const int r0 = (lane >> 4) * 4;
  const int col = w * 16 + c0;
  const float bv = fc_out_b[col];
#pragma unroll
  for (int rr = 0; rr < 4; ++rr) {
    int brow = row0 + r0 + rr;
    out[((size_t)brow * T_ + tlog) * V_ + col] = acc[rr] + bv;
  }
}

// ================= D2: (pw0(t) + gx1(t) GEMM) || gh1(t) GEMM =================
// gx1 blocks: bid<384: mt=bid/6 (32-row tile), nt=bid%6 (256-col tile).
// Phase1: pw0 for the 32 rows (redundant across 6 n-tiles), h0n -> LDS (swizzled bf16).
// Phase2: gx1 tile = LDS-A (32x512) @ W_ih1 (256x512)^T.
__global__ __launch_bounds__(256) void k_D2(
    const short* __restrict__ zgx, const short* __restrict__ egx,
    const short* __restrict__ gh0, const int* __restrict__ target,
    const float* __restrict__ h0f_prev, float* __restrict__ h0f_new,
    short* __restrict__ h0b_new,
    const short* __restrict__ Wb_ih1, const float* __restrict__ b_ih1,
    short* __restrict__ gx1,
    const short* __restrict__ h1b, const short* __restrict__ Wb_hh1,
    const float* __restrict__ b_hh1, short* __restrict__ gh1,
    const int t) {
  const int bid = blockIdx.x;
  const int tid = threadIdx.x;
  __shared__ __align__(16) char hns[32 * 1024];  // 32 rows x 512 bf16, swizzled
  if (bid >= 384) {
    // gh1 GEMM: 384 blocks, 64x128 tiles
    const int g = bid - 384;
    const int lane = tid & 63, wid = tid >> 6;
    const int wm = wid >> 1, wn = wid & 1;
    const int mt = g / 12, nt = g % 12;
    const int arow = mt * 64 + wm * 32;
    const int bcol = nt * 128 + wn * 64;
    f32x4 acc[2][4] = {};
    gemm_wave_global<2, 4>(h1b, Wb_hh1, H_, arow, bcol, acc);
    epi_store_bf16<2, 4>(gh1, b_hh1, H3, arow, bcol, acc);
    return;
  }
  const int mt = bid / 6, nt = bid % 6;
  const int mbase = mt * 32;
  // ---- phase 1: pw0 for rows [mbase, mbase+32)
#pragma unroll 1
  for (int c = 0; c < 8; ++c) {
    int f = c * 2048 + tid * 8;
    int rl = f >> 9, j = f & 511;
    int row = mbase + rl;
    int tok = (t == 0) ? 1 : target[(size_t)row * T_ + (t - 1)];
    const short* zg = zgx + (size_t)row * H3 + j;
    const short* eg = egx + (size_t)tok * H3 + j;
    const short* gh = gh0 + (size_t)row * H3 + j;
    const float* hf = h0f_prev + (size_t)row * H_ + j;
    bf16x8 zr = *(const bf16x8*)(zg);
    bf16x8 zz = *(const bf16x8*)(zg + H_);
    bf16x8 zn = *(const bf16x8*)(zg + 2 * H_);
    bf16x8 er = *(const bf16x8*)(eg);
    bf16x8 ez = *(const bf16x8*)(eg + H_);
    bf16x8 en = *(const bf16x8*)(eg + 2 * H_);
    bf16x8 hr = *(const bf16x8*)(gh);
    bf16x8 hz = *(const bf16x8*)(gh + H_);
    bf16x8 hn = *(const bf16x8*)(gh + 2 * H_);
    float4 hp0 = *(const float4*)(hf);
    float4 hp1 = *(const float4*)(hf + 4);
    float hp[8] = {hp0.x, hp0.y, hp0.z, hp0.w, hp1.x, hp1.y, hp1.z, hp1.w};
    float hv[8];
    bf16x8 ov;
#pragma unroll
    for (int e = 0; e < 8; ++e) {
      hv[e] = gru_one(b2f(zr[e]) + b2f(er[e]), b2f(zz[e]) + b2f(ez[e]),
                      b2f(zn[e]) + b2f(en[e]),
                      b2f(hr[e]), b2f(hz[e]), b2f(hn[e]), hp[e]);
      ov[e] = f2b(hv[e]);
    }
    *(bf16x8*)(hns + (rl << 10) + ((j << 1) ^ ((rl & 7) << 4))) = ov;
    if (nt == 0) {
      float* ho = h0f_new + (size_t)row * H_ + j;
      *(float4*)(ho) = make_float4(hv[0], hv[1], hv[2], hv[3]);
      *(float4*)(ho + 4) = make_float4(hv[4], hv[5], hv[6], hv[7]);
      *(bf16x8*)(h0b_new + (size_t)row * H_ + j) = ov;
    }
  }
  __syncthreads();
  // ---- phase 2: gx1 tile 32x256, waves 1x4 (each wave 32x64)
  const int wid = tid >> 6;
  const int bcol = nt * 256 + wid * 64;
  f32x4 acc[2][4] = {};
  gemm_wave_ldsA<2, 4>(hns, Wb_ih1, 0, bcol, acc);
  epi_store_bf16<2, 4>(gx1, b_ih1, H3, mbase, bcol, acc);
}

extern "C" void kernel_launch(void* const* d_in, const int* in_sizes, int n_in,
                              void* d_out, int out_size, void* d_ws, size_t ws_size,
                              hipStream_t stream) {
  const float* z           = (const float*)d_in[0];
  const int*   target      = (const int*)d_in[1];
  const float* embed       = (const float*)d_in[2];
  const float* fc_hidden_w = (const float*)d_in[3];
  const float* fc_hidden_b = (const float*)d_in[4];
  const float* W_ih0       = (const float*)d_in[5];
  const float* W_hh0       = (const float*)d_in[6];
  const float* b_ih0       = (const float*)d_in[7];
  const float* b_hh0       = (const float*)d_in[8];
  const float* W_ih1       = (const float*)d_in[9];
  const float* W_hh1       = (const float*)d_in[10];
  const float* b_ih1       = (const float*)d_in[11];
  const float* b_hh1       = (const float*)d_in[12];
  const float* fc_out_w    = (const float*)d_in[13];
  const float* fc_out_b    = (const float*)d_in[14];
  float* out = (float*)d_out;

  char* ws = (char*)d_ws;
  size_t off = 0;
  auto alloc = [&](size_t bytes) -> void* {
    off = (off + 255) & ~(size_t)255;
    void* p = ws + off;
    off += bytes;
    return p;
  };
  float* h0f0   = (float*)alloc((size_t)B_ * H_ * 4);
  float* h0f1   = (float*)alloc((size_t)B_ * H_ * 4);
  float* h1f    = (float*)alloc((size_t)B_ * H_ * 4);
  short* h0b0   = (short*)alloc((size_t)B_ * H_ * 2);
  short* h0b1   = (short*)alloc((size_t)B_ * H_ * 2);
  short* h1b    = (short*)alloc((size_t)B_ * H_ * 2);
  short* gh0    = (short*)alloc((size_t)B_ * H3 * 2);
  short* gh1    = (short*)alloc((size_t)B_ * H3 * 2);
  short* gx1    = (short*)alloc((size_t)B_ * H3 * 2);
  short* zgx    = (short*)alloc((size_t)B_ * H3 * 2);
  short* egx    = (short*)alloc((size_t)V_ * H3 * 2);
  short* Wb_hh0 = (short*)alloc((size_t)H3 * H_ * 2);
  short* Wb_ih1 = (short*)alloc((size_t)H3 * H_ * 2);
  short* Wb_hh1 = (short*)alloc((size_t)H3 * H_ * 2);
  short* Wb_out = (short*)alloc((size_t)V_ * H_ * 2);
  short* Wb_ih0z= (short*)alloc((size_t)H3 * LAT_ * 2);
  short* Wb_fch = (short*)alloc((size_t)2 * H_ * LAT_ * 2);
  short* z_b    = (short*)alloc((size_t)B_ * LAT_ * 2);
  if (off > ws_size) return;

  k_prep0<<<2048, 256, 0, stream>>>(W_hh0, W_ih1, W_hh1, fc_out_w, W_ih0, fc_hidden_w,
                                    z, Wb_hh0, Wb_ih1, Wb_hh1, Wb_out, Wb_ih0z, Wb_fch, z_b);
  k_prep_emb<<<64, 256, 0, stream>>>(embed, W_ih0, egx);
  k_prep1<<<320, 256, 0, stream>>>(z_b, Wb_ih0z, Wb_fch, b_ih0, fc_hidden_b,
                                   zgx, h0f0, h1f, h0b0, h1b);

  float* h0f[2] = {h0f0, h0f1};
  short* h0b[2] = {h0b0, h0b1};
  for (int t = 0; t < T_; ++t) {
    int p = t & 1;
    int grid1 = (t == 0) ? 384 : 512;
    k_D1<<<grid1, 256, 0, stream>>>(h0b[p], Wb_hh0, b_hh0, gh0, 384, t,
                                    gx1, gh1, h1f, h1b, Wb_out, fc_out_b, out);
    k_D2<<<768, 256, 0, stream>>>(zgx, egx, gh0, target, h0f[p], h0f[p ^ 1], h0b[p ^ 1],
                                  Wb_ih1, b_ih1, gx1, h1b, Wb_hh1, b_hh1, gh1, t);
  }
  // final pw1 + logits for t = T-1
  k_D1<<<128, 256, 0, stream>>>(h0b[0], Wb_hh0, b_hh0, gh0, 0, T_,
                                gx1, gh1, h1f, h1b, Wb_out, fc_out_b, out);
}

// Round 4
// 5434.001 us; speedup vs baseline: 1.4902x; 1.4089x over previous
//
#include <hip/hip_runtime.h>
#include <hip/hip_bf16.h>

#define DI __device__ __forceinline__

typedef short bf16x8 __attribute__((ext_vector_type(8)));
typedef float f32x4 __attribute__((ext_vector_type(4)));

constexpr int B_ = 2048, T_ = 120, V_ = 64, E_ = 128, H_ = 512, LAT_ = 256;
constexpr int H3 = 1536;  // 3*H

DI short f2b(float f) {
  union { __hip_bfloat16 h; short s; } u;
  u.h = __float2bfloat16(f);
  return u.s;
}
DI float b2f(short s) {
  union { unsigned u; float f; } x;
  x.u = (unsigned)(unsigned short)s << 16;
  return x.f;
}
DI float sigm(float x) { return 1.f / (1.f + __expf(-x)); }
DI float tanh_f(float x) {
  x = fminf(15.f, fmaxf(-15.f, x));
  float e = __expf(2.f * x);
  return (e - 1.f) / (e + 1.f);
}
DI float gru_one(float xr, float xz, float xn, float hr, float hz, float hn, float hp) {
  float r = sigm(xr + hr);
  float u = sigm(xz + hz);
  float nn = tanh_f(xn + r * hn);
  return (1.f - u) * nn + u * hp;
}

// ======== register staging: global -> regs (issue early) -> swizzled ds_write (late) ========
// Chunk = ROWS x BK bf16, row-major K-contig source. LDS row stride = BK*2 bytes.
// 16B slot s of row r lands at slot s ^ (r & (BK/8 - 1)).  256 threads per block.
template <int ROWS, int BK, int NV>
DI void rs_load(const short* __restrict__ G, int row0, int K, int kk, bf16x8 (&v)[NV]) {
  constexpr int SLOTS = BK / 8;
  constexpr int RPP = 2048 / BK;  // rows covered per pass by 256 threads
  static_assert(NV == ROWS / RPP, "NV mismatch");
  const int tid = threadIdx.x;
  const int rl = tid / SLOTS, sl = tid % SLOTS;
#pragma unroll
  for (int p = 0; p < NV; ++p)
    v[p] = *(const bf16x8*)(G + (size_t)(row0 + p * RPP + rl) * K + kk + sl * 8);
}
template <int ROWS, int BK, int NV>
DI void rs_write(char* __restrict__ lds, bf16x8 (&v)[NV]) {
  constexpr int SLOTS = BK / 8;
  constexpr int RPP = 2048 / BK;
  const int tid = threadIdx.x;
  const int rl = tid / SLOTS, sl = tid % SLOTS;
#pragma unroll
  for (int p = 0; p < NV; ++p) {
    int row = p * RPP + rl;
    *(bf16x8*)(lds + row * (SLOTS * 16) + ((sl ^ (row & (SLOTS - 1))) * 16)) = v[p];
  }
}
// fragment read from a BK-chunk LDS tile (kk = element offset within chunk, multiple of 8)
template <int BK>
DI bf16x8 fragL(const char* __restrict__ lds, int row, int kk) {
  return *(const bf16x8*)(lds + row * (BK * 2) + ((kk << 1) ^ ((row & (BK / 8 - 1)) << 4)));
}

// ======== staged 64x128 GEMM: C[64x128] = A[64x512] @ W[128x512]^T + bias, bf16 out ========
// 4 waves as 2x2 (wave tile 32x64). LDS: As 8KB @0, Bs 16KB @8192 (24KB total, single-buf).
DI void gemm_64x128_rs(const short* __restrict__ A, const short* __restrict__ Bw,
                       const float* __restrict__ bias, short* __restrict__ C,
                       int arow, int bcol, char* lds) {
  char* As = lds;
  char* Bs = lds + 8192;
  const int tid = threadIdx.x, lane = tid & 63, wid = tid >> 6;
  const int wm = wid >> 1, wn = wid & 1;
  const int r = lane & 15, ko = (lane >> 4) * 8;
  bf16x8 va[2], vb[4];
  f32x4 acc[2][4] = {};
  rs_load<64, 64, 2>(A, arow, H_, 0, va);
  rs_load<128, 64, 4>(Bw, bcol, H_, 0, vb);
  rs_write<64, 64, 2>(As, va);
  rs_write<128, 64, 4>(Bs, vb);
  __syncthreads();
  for (int c = 0; c < 8; ++c) {
    if (c < 7) {
      rs_load<64, 64, 2>(A, arow, H_, (c + 1) * 64, va);
      rs_load<128, 64, 4>(Bw, bcol, H_, (c + 1) * 64, vb);
    }
#pragma unroll
    for (int kh = 0; kh < 2; ++kh) {
      const int kkk = kh * 32 + ko;
      bf16x8 a[2], b[4];
#pragma unroll
      for (int i = 0; i < 2; ++i) a[i] = fragL<64>(As, wm * 32 + i * 16 + r, kkk);
#pragma unroll
      for (int j = 0; j < 4; ++j) b[j] = fragL<64>(Bs, wn * 64 + j * 16 + r, kkk);
#pragma unroll
      for (int i = 0; i < 2; ++i)
#pragma unroll
        for (int j = 0; j < 4; ++j)
          acc[i][j] = __builtin_amdgcn_mfma_f32_16x16x32_bf16(a[i], b[j], acc[i][j], 0, 0, 0);
    }
    __syncthreads();  // all frag reads of this chunk done
    if (c < 7) {
      rs_write<64, 64, 2>(As, va);
      rs_write<128, 64, 4>(Bs, vb);
      __syncthreads();  // next chunk visible
    }
  }
  const int r0 = (lane >> 4) * 4, c0 = lane & 15;
#pragma unroll
  for (int i = 0; i < 2; ++i)
#pragma unroll
    for (int j = 0; j < 4; ++j) {
      int col = bcol + wn * 64 + j * 16 + c0;
      float bv = bias[col];
#pragma unroll
      for (int rr = 0; rr < 4; ++rr)
        C[(size_t)(arow + wm * 32 + i * 16 + r0 + rr) * H3 + col] = f2b(acc[i][j][rr] + bv);
    }
}

// ---- direct-global fragment GEMM (prep only, runs once)
template <int MI, int NJ>
DI void gemm_wave_global(const short* __restrict__ A, const short* __restrict__ B,
                         const int K, const int arow, const int bcol,
                         f32x4 (&acc)[MI][NJ]) {
  const int lane = threadIdx.x & 63;
  const int r = lane & 15, ko = (lane >> 4) * 8;
  const short* Ap = A + (size_t)(arow + r) * K + ko;
  const short* Bp = B + (size_t)(bcol + r) * K + ko;
  for (int kk = 0; kk < K; kk += 32) {
    bf16x8 a[MI], b[NJ];
#pragma unroll
    for (int i = 0; i < MI; ++i) a[i] = *(const bf16x8*)(Ap + (size_t)i * 16 * K + kk);
#pragma unroll
    for (int j = 0; j < NJ; ++j) b[j] = *(const bf16x8*)(Bp + (size_t)j * 16 * K + kk);
#pragma unroll
    for (int i = 0; i < MI; ++i)
#pragma unroll
      for (int j = 0; j < NJ; ++j)
        acc[i][j] = __builtin_amdgcn_mfma_f32_16x16x32_bf16(a[i], b[j], acc[i][j], 0, 0, 0);
  }
}

template <int MI, int NJ>
DI void epi_store_bf16(short* __restrict__ C, const float* __restrict__ bias,
                       const int N, const int arow, const int bcol, f32x4 (&acc)[MI][NJ]) {
  const int lane = threadIdx.x & 63;
  const int r0 = (lane >> 4) * 4, c0 = lane & 15;
#pragma unroll
  for (int i = 0; i < MI; ++i)
#pragma unroll
    for (int j = 0; j < NJ; ++j) {
      int col = bcol + j * 16 + c0;
      float bv = bias[col];
#pragma unroll
      for (int rr = 0; rr < 4; ++rr)
        C[(size_t)(arow + i * 16 + r0 + rr) * N + col] = f2b(acc[i][j][rr] + bv);
    }
}

// ================= prep kernels =================
__global__ __launch_bounds__(256) void k_prep0(
    const float* __restrict__ W_hh0, const float* __restrict__ W_ih1,
    const float* __restrict__ W_hh1, const float* __restrict__ fc_out_w,
    const float* __restrict__ W_ih0, const float* __restrict__ fc_hidden_w,
    const float* __restrict__ z,
    short* Wb_hh0, short* Wb_ih1, short* Wb_hh1, short* Wb_out,
    short* Wb_ih0z, short* Wb_fch, short* z_b) {
  const int n1 = H3 * H_;
  const int n2 = V_ * H_;
  const int n3 = H3 * LAT_;
  const int n4 = (2 * H_) * LAT_;
  const int n5 = B_ * LAT_;
  const int total = n1 * 3 + n2 + n3 + n4 + n5;
  for (int i = blockIdx.x * blockDim.x + threadIdx.x; i < total;
       i += gridDim.x * blockDim.x) {
    int idx = i;
    if (idx < n1) { Wb_hh0[idx] = f2b(W_hh0[idx]); continue; }
    idx -= n1;
    if (idx < n1) { Wb_ih1[idx] = f2b(W_ih1[idx]); continue; }
    idx -= n1;
    if (idx < n1) { Wb_hh1[idx] = f2b(W_hh1[idx]); continue; }
    idx -= n1;
    if (idx < n2) { Wb_out[idx] = f2b(fc_out_w[idx]); continue; }
    idx -= n2;
    if (idx < n3) {
      int n = idx >> 8, k = idx & 255;
      Wb_ih0z[idx] = f2b(W_ih0[(size_t)n * (E_ + LAT_) + E_ + k]);
      continue;
    }
    idx -= n3;
    if (idx < n4) { Wb_fch[idx] = f2b(fc_hidden_w[idx]); continue; }
    idx -= n4;
    z_b[idx] = f2b(z[idx]);
  }
}

__global__ __launch_bounds__(256) void k_prep_emb(const float* __restrict__ embed,
                                                  const float* __restrict__ W_ih0,
                                                  short* __restrict__ egx) {
  __shared__ float er[E_];
  int v = blockIdx.x;
  for (int e = threadIdx.x; e < E_; e += blockDim.x) er[e] = embed[(size_t)v * E_ + e];
  __syncthreads();
  for (int n = threadIdx.x; n < H3; n += blockDim.x) {
    const float* w = W_ih0 + (size_t)n * (E_ + LAT_);
    float acc = 0.f;
#pragma unroll 8
    for (int e = 0; e < E_; ++e) acc += er[e] * w[e];
    egx[(size_t)v * H3 + n] = f2b(acc);
  }
}

__global__ __launch_bounds__(256) void k_prep1(
    const short* __restrict__ z_b, const short* __restrict__ Wb_ih0z,
    const short* __restrict__ Wb_fch, const float* __restrict__ b_ih0,
    const float* __restrict__ fc_hidden_b,
    short* zgx, float* h0f, float* h1f, short* h0b, short* h1b) {
  const int bid = blockIdx.x;
  const int mtile = bid / 20, ntile = bid % 20;
  const int tid = threadIdx.x, lane = tid & 63, wid = tid >> 6;
  const int wm = wid >> 1, wn = wid & 1;
  const int arow = mtile * 128 + wm * 64;
  f32x4 acc[4][4] = {};
  if (ntile < 12) {
    int bcol = ntile * 128 + wn * 64;
    gemm_wave_global<4, 4>(z_b, Wb_ih0z, LAT_, arow, bcol, acc);
    epi_store_bf16<4, 4>(zgx, b_ih0, H3, arow, bcol, acc);
  } else {
    int bcol = (ntile - 12) * 128 + wn * 64;
    gemm_wave_global<4, 4>(z_b, Wb_fch, LAT_, arow, bcol, acc);
    const int r0 = (lane >> 4) * 4, c0 = lane & 15;
#pragma unroll
    for (int i = 0; i < 4; ++i)
#pragma unroll
      for (int j = 0; j < 4; ++j) {
        int col = bcol + j * 16 + c0;
        float bv = fc_hidden_b[col];
#pragma unroll
        for (int rr = 0; rr < 4; ++rr) {
          int row = arow + i * 16 + r0 + rr;
          float v = acc[i][j][rr] + bv;
          if (col < H_) {
            h0f[(size_t)row * H_ + col] = v;
            h0b[(size_t)row * H_ + col] = f2b(v);
          } else {
            h1f[(size_t)row * H_ + (col - H_)] = v;
            h1b[(size_t)row * H_ + (col - H_)] = f2b(v);
          }
        }
      }
  }
}

// ================= D1: gh0(t) GEMM (staged) || pw1(t-1)+logits(t-1) =================
__global__ __launch_bounds__(256) void k_D1(
    const short* __restrict__ h0b_cur, const short* __restrict__ Wb_hh0,
    const float* __restrict__ b_hh0, short* __restrict__ gh0,
    const int gblocks, const int t,
    const short* __restrict__ gx1, const short* __restrict__ gh1,
    float* __restrict__ h1f, short* __restrict__ h1b,
    const short* __restrict__ Wb_out, const float* __restrict__ fc_out_b,
    float* __restrict__ out) {
  extern __shared__ char smem[];
  const int bid = blockIdx.x;
  const int tid = threadIdx.x;
  if (bid < gblocks) {
    gemm_64x128_rs(h0b_cur, Wb_hh0, b_hh0, gh0, (bid / 12) * 64, (bid % 12) * 128, smem);
    return;
  }
  // pw1 + logits for step t-1; 16 rows per block
  short* sh = (short*)smem;
  const int pwblk = bid - gblocks;
  const int row0 = pwblk * 16;
  const int tlog = t - 1;
#pragma unroll 1
  for (int c = 0; c < 4; ++c) {
    int f = c * 2048 + tid * 8;
    int rl = f >> 9, j = f & 511;
    int row = row0 + rl;
    const short* gx = gx1 + (size_t)row * H3 + j;
    const short* gh = gh1 + (size_t)row * H3 + j;
    float* hf = h1f + (size_t)row * H_ + j;
    bf16x8 xr = *(const bf16x8*)(gx);
    bf16x8 xz = *(const bf16x8*)(gx + H_);
    bf16x8 xn = *(const bf16x8*)(gx + 2 * H_);
    bf16x8 hr = *(const bf16x8*)(gh);
    bf16x8 hz = *(const bf16x8*)(gh + H_);
    bf16x8 hn = *(const bf16x8*)(gh + 2 * H_);
    float4 hp0 = *(const float4*)(hf);
    float4 hp1 = *(const float4*)(hf + 4);
    float hp[8] = {hp0.x, hp0.y, hp0.z, hp0.w, hp1.x, hp1.y, hp1.z, hp1.w};
    float hv[8];
    bf16x8 ov;
#pragma unroll
    for (int e = 0; e < 8; ++e) {
      hv[e] = gru_one(b2f(xr[e]), b2f(xz[e]), b2f(xn[e]),
                      b2f(hr[e]), b2f(hz[e]), b2f(hn[e]), hp[e]);
      ov[e] = f2b(hv[e]);
    }
    *(float4*)(hf) = make_float4(hv[0], hv[1], hv[2], hv[3]);
    *(float4*)(hf + 4) = make_float4(hv[4], hv[5], hv[6], hv[7]);
    *(bf16x8*)(h1b + (size_t)row * H_ + j) = ov;
    *(bf16x8*)(&sh[rl * 520 + j]) = ov;
  }
  __syncthreads();
  const int lane = tid & 63, w = tid >> 6;
  const int c0 = lane & 15, ko = (lane >> 4) * 8;
  f32x4 acc = {};
  const short* wb = Wb_out + (size_t)(w * 16 + c0) * H_ + ko;
  const short* ap = &sh[c0 * 520 + ko];
#pragma unroll
  for (int m = 0; m < 16; ++m) {
    bf16x8 a = *(const bf16x8*)(ap + m * 32);
    bf16x8 bw = *(const bf16x8*)(wb + m * 32);
    acc = __builtin_amdgcn_mfma_f32_16x16x32_bf16(a, bw, acc, 0, 0, 0);
  }
  const int r0 = (lane >> 4) * 4;
  const int col = w * 16 + c0;
  const float bv = fc_out_b[col];
#pragma unroll
  for (int rr = 0; rr < 4; ++rr) {
    int brow = row0 + r0 + rr;
    out[((size_t)brow * T_ + tlog) * V_ + col] = acc[rr] + bv;
  }
}

// ================= D2: (pw0(t) + gx1(t) staged GEMM) || gh1(t) staged GEMM =================
__global__ __launch_bounds__(256) void k_D2(
    const short* __restrict__ zgx, const short* __restrict__ egx,
    const short* __restrict__ gh0, const int* __restrict__ target,
    const float* __restrict__ h0f_prev, float* __restrict__ h0f_new,
    short* __restrict__ h0b_new,
    const short* __restrict__ Wb_ih1, const float* __restrict__ b_ih1,
    short* __restrict__ gx1,
    const short* __restrict__ h1b, const short* __restrict__ Wb_hh1,
    const float* __restrict__ b_hh1, short* __restrict__ gh1,
    const int t) {
  extern __shared__ char smem[];
  const int bid = blockIdx.x;
  const int tid = threadIdx.x;
  if (bid >= 384) {
    const int g = bid - 384;
    gemm_64x128_rs(h1b, Wb_hh1, b_hh1, gh1, (g / 12) * 64, (g % 12) * 128, smem);
    return;
  }
  // gx1 blocks: mt in [0,64) owns 32 rows; nt in [0,6) owns 256 weight cols.
  const int mt = bid / 6, nt = bid % 6;
  const int mbase = mt * 32, nb = nt * 256;
  char* hns = smem;            // 32 rows x 512 bf16, swizzled, 32KB
  char* Bs = smem + 32768;     // 256 rows x 32 bf16 chunk, 16KB
  bf16x8 vb[4];
  rs_load<256, 32, 4>(Wb_ih1, nb, H_, 0, vb);  // chunk0 issue early; hides under pw0
  // ---- pw0 for rows [mbase, mbase+32)
#pragma unroll 1
  for (int c = 0; c < 8; ++c) {
    int f = c * 2048 + tid * 8;
    int rl = f >> 9, j = f & 511;
    int row = mbase + rl;
    int tok = (t == 0) ? 1 : target[(size_t)row * T_ + (t - 1)];
    const short* zg = zgx + (size_t)row * H3 + j;
    const short* eg = egx + (size_t)tok * H3 + j;
    const short* gh = gh0 + (size_t)row * H3 + j;
    const float* hf = h0f_prev + (size_t)row * H_ + j;
    bf16x8 zr = *(const bf16x8*)(zg);
    bf16x8 zz = *(const bf16x8*)(zg + H_);
    bf16x8 zn = *(const bf16x8*)(zg + 2 * H_);
    bf16x8 er = *(const bf16x8*)(eg);
    bf16x8 ez = *(const bf16x8*)(eg + H_);
    bf16x8 en = *(const bf16x8*)(eg + 2 * H_);
    bf16x8 hr = *(const bf16x8*)(gh);
    bf16x8 hz = *(const bf16x8*)(gh + H_);
    bf16x8 hn = *(const bf16x8*)(gh + 2 * H_);
    float4 hp0 = *(const float4*)(hf);
    float4 hp1 = *(const float4*)(hf + 4);
    float hp[8] = {hp0.x, hp0.y, hp0.z, hp0.w, hp1.x, hp1.y, hp1.z, hp1.w};
    float hv[8];
    bf16x8 ov;
#pragma unroll
    for (int e = 0; e < 8; ++e) {
      hv[e] = gru_one(b2f(zr[e]) + b2f(er[e]), b2f(zz[e]) + b2f(ez[e]),
                      b2f(zn[e]) + b2f(en[e]),
                      b2f(hr[e]), b2f(hz[e]), b2f(hn[e]), hp[e]);
      ov[e] = f2b(hv[e]);
    }
    *(bf16x8*)(hns + (rl << 10) + ((j << 1) ^ ((rl & 7) << 4))) = ov;
    if (nt == 0) {
      float* ho = h0f_new + (size_t)row * H_ + j;
      *(float4*)(ho) = make_float4(hv[0], hv[1], hv[2], hv[3]);
      *(float4*)(ho + 4) = make_float4(hv[4], hv[5], hv[6], hv[7]);
      *(bf16x8*)(h0b_new + (size_t)row * H_ + j) = ov;
    }
  }
  __syncthreads();                 // hns visible
  rs_write<256, 32, 4>(Bs, vb);    // chunk0 into LDS
  __syncthreads();                 // Bs visible
  // ---- gx1 tile 32x256: 4 waves 1x4 (wave tile 32x64); A from hns, B chunked BK=32
  const int lane = tid & 63, wid = tid >> 6;
  const int r = lane & 15, ko = (lane >> 4) * 8;
  f32x4 acc[2][4] = {};
  for (int c = 0; c < 16; ++c) {
    if (c < 15) rs_load<256, 32, 4>(Wb_ih1, nb, H_, (c + 1) * 32, vb);
    bf16x8 a[2], b[4];
#pragma unroll
    for (int i = 0; i < 2; ++i) {
      int row = i * 16 + r;
      a[i] = *(const bf16x8*)(hns + (row << 10) + ((((c * 32 + ko) << 1)) ^ ((row & 7) << 4)));
    }
#pragma unroll
    for (int j = 0; j < 4; ++j) b[j] = fragL<32>(Bs, wid * 64 + j * 16 + r, ko);
#pragma unroll
    for (int i = 0; i < 2; ++i)
#pragma unroll
      for (int j = 0; j < 4; ++j)
        acc[i][j] = __builtin_amdgcn_mfma_f32_16x16x32_bf16(a[i], b[j], acc[i][j], 0, 0, 0);
    __syncthreads();  // reads of Bs done
    if (c < 15) {
      rs_write<256, 32, 4>(Bs, vb);
      __syncthreads();  // next chunk visible
    }
  }
  const int r0 = (lane >> 4) * 4, c0 = lane & 15;
#pragma unroll
  for (int i = 0; i < 2; ++i)
#pragma unroll
    for (int j = 0; j < 4; ++j) {
      int col = nb + wid * 64 + j * 16 + c0;
      float bv = b_ih1[col];
#pragma unroll
      for (int rr = 0; rr < 4; ++rr)
        gx1[(size_t)(mbase + i * 16 + r0 + rr) * H3 + col] = f2b(acc[i][j][rr] + bv);
    }
}

extern "C" void kernel_launch(void* const* d_in, const int* in_sizes, int n_in,
                              void* d_out, int out_size, void* d_ws, size_t ws_size,
                              hipStream_t stream) {
  const float* z           = (const float*)d_in[0];
  const int*   target      = (const int*)d_in[1];
  const float* embed       = (const float*)d_in[2];
  const float* fc_hidden_w = (const float*)d_in[3];
  const float* fc_hidden_b = (const float*)d_in[4];
  const float* W_ih0       = (const float*)d_in[5];
  const float* W_hh0       = (const float*)d_in[6];
  const float* b_ih0       = (const float*)d_in[7];
  const float* b_hh0       = (const float*)d_in[8];
  const float* W_ih1       = (const float*)d_in[9];
  const float* W_hh1       = (const float*)d_in[10];
  const float* b_ih1       = (const float*)d_in[11];
  const float* b_hh1       = (const float*)d_in[12];
  const float* fc_out_w    = (const float*)d_in[13];
  const float* fc_out_b    = (const float*)d_in[14];
  float* out = (float*)d_out;

  char* ws = (char*)d_ws;
  size_t off = 0;
  auto alloc = [&](size_t bytes) -> void* {
    off = (off + 255) & ~(size_t)255;
    void* p = ws + off;
    off += bytes;
    return p;
  };
  float* h0f0   = (float*)alloc((size_t)B_ * H_ * 4);
  float* h0f1   = (float*)alloc((size_t)B_ * H_ * 4);
  float* h1f    = (float*)alloc((size_t)B_ * H_ * 4);
  short* h0b0   = (short*)alloc((size_t)B_ * H_ * 2);
  short* h0b1   = (short*)alloc((size_t)B_ * H_ * 2);
  short* h1b    = (short*)alloc((size_t)B_ * H_ * 2);
  short* gh0    = (short*)alloc((size_t)B_ * H3 * 2);
  short* gh1    = (short*)alloc((size_t)B_ * H3 * 2);
  short* gx1    = (short*)alloc((size_t)B_ * H3 * 2);
  short* zgx    = (short*)alloc((size_t)B_ * H3 * 2);
  short* egx    = (short*)alloc((size_t)V_ * H3 * 2);
  short* Wb_hh0 = (short*)alloc((size_t)H3 * H_ * 2);
  short* Wb_ih1 = (short*)alloc((size_t)H3 * H_ * 2);
  short* Wb_hh1 = (short*)alloc((size_t)H3 * H_ * 2);
  short* Wb_out = (short*)alloc((size_t)V_ * H_ * 2);
  short* Wb_ih0z= (short*)alloc((size_t)H3 * LAT_ * 2);
  short* Wb_fch = (short*)alloc((size_t)2 * H_ * LAT_ * 2);
  short* z_b    = (short*)alloc((size_t)B_ * LAT_ * 2);
  if (off > ws_size) return;

  k_prep0<<<2048, 256, 0, stream>>>(W_hh0, W_ih1, W_hh1, fc_out_w, W_ih0, fc_hidden_w,
                                    z, Wb_hh0, Wb_ih1, Wb_hh1, Wb_out, Wb_ih0z, Wb_fch, z_b);
  k_prep_emb<<<64, 256, 0, stream>>>(embed, W_ih0, egx);
  k_prep1<<<320, 256, 0, stream>>>(z_b, Wb_ih0z, Wb_fch, b_ih0, fc_hidden_b,
                                   zgx, h0f0, h1f, h0b0, h1b);

  float* h0f[2] = {h0f0, h0f1};
  short* h0b[2] = {h0b0, h0b1};
  for (int t = 0; t < T_; ++t) {
    int p = t & 1;
    int grid1 = (t == 0) ? 384 : 512;
    k_D1<<<grid1, 256, 24576, stream>>>(h0b[p], Wb_hh0, b_hh0, gh0, 384, t,
                                        gx1, gh1, h1f, h1b, Wb_out, fc_out_b, out);
    k_D2<<<768, 256, 49152, stream>>>(zgx, egx, gh0, target, h0f[p], h0f[p ^ 1], h0b[p ^ 1],
                                      Wb_ih1, b_ih1, gx1, h1b, Wb_hh1, b_hh1, gh1, t);
  }
  k_D1<<<128, 256, 24576, stream>>>(h0b[0], Wb_hh0, b_hh0, gh0, 0, T_,
                                    gx1, gh1, h1f, h1b, Wb_out, fc_out_b, out);
}